// Round 17
// baseline (309.799 us; speedup 1.0000x reference)
//
#include <hip/hip_runtime.h>
#include <cstdint>
#include <cstddef>

#define NB 32
#define NN 1024
#define ND 256
#define KNNK 16

typedef __attribute__((ext_vector_type(8))) short bf16x8;
typedef __attribute__((ext_vector_type(4))) float f32x4;
typedef __attribute__((ext_vector_type(4))) short short4v;

// Round-to-nearest-even bf16 split (identical arithmetic to v12-v16's
// pack_bf16_split; just returns the two halves separately).
__device__ __forceinline__ void bf16_split(float v, unsigned short& h,
                                           unsigned short& l) {
    uint32_t u  = __float_as_uint(v);
    uint32_t hi = (u + 0x7fffu + ((u >> 16) & 1u)) >> 16;
    float    hf = __uint_as_float(hi << 16);
    uint32_t g  = __float_as_uint(v - hf);
    uint32_t lo = (g + 0x7fffu + ((g >> 16) & 1u)) >> 16;
    h = (unsigned short)hi;
    l = (unsigned short)lo;
}

// Fragment-tiled plane layout (shorts):
//   plane[rt][c][lh][lr][i] ; rt = flat_row>>4 (0..2047), c = e>>5 (0..7),
//   lh = (e>>3)&3, lr = flat_row&15, i = e&7
//   linear: rt*4096 + c*512 + lh*128 + lr*8 + i
// A wave's MFMA fragment load (fixed rt, c) = lanes (lh,lr) reading
// consecutive 16B chunks -> one fully-coalesced 1KB load per fragment.

// ---------------------------------------------------------------------------
// Kernel A v17: v16's compute verbatim (bit-identical accQ/accK), but stores
// go to 4 separate bf16 planes in fragment-tiled layout (h/l split done here
// ONCE instead of 40 v_perms per chunk per wave in score).
// ---------------------------------------------------------------------------
__global__ __launch_bounds__(256) void proj_kernel(
    const float* __restrict__ x, const float* __restrict__ pos,
    const float* __restrict__ wq, const float* __restrict__ bq,
    const float* __restrict__ wk, const float* __restrict__ bk,
    unsigned short* __restrict__ Qh, unsigned short* __restrict__ Ql,
    unsigned short* __restrict__ Kh, unsigned short* __restrict__ Kl)
{
    __shared__ __align__(16) float Hs [16][68];
    __shared__ __align__(16) float WsQ[16][68];
    __shared__ __align__(16) float WsK[16][68];

    const int tid = threadIdx.x;
    const int tx = tid & 15;          // e microtile index
    const int ty = tid >> 4;          // row microtile index
    const int bm = blockIdx.x >> 2;   // 0..511 row tiles
    const int be = blockIdx.x & 3;    // 0..3 e tiles (both Q and K)
    const int rowBase = bm << 6;      // flattened b*1024 + n
    const int n0 = rowBase & 1023;
    const int e0 = be << 6;

    const int sr = tid >> 2;          // 0..63
    const int sd = (tid & 3) << 2;    // 0,4,8,12

    float accQ[4][4], accK[4][4];
    #pragma unroll
    for (int i = 0; i < 4; ++i)
        #pragma unroll
        for (int j = 0; j < 4; ++j) { accQ[i][j] = 0.0f; accK[i][j] = 0.0f; }

    #pragma unroll 1
    for (int dc = 0; dc < 256; dc += 16) {
        const float4 xv  = *(const float4*)&x  [(size_t)(rowBase + sr) * 256 + dc + sd];
        const float4 pv  = *(const float4*)&pos[(size_t)(n0 + sr) * 256 + dc + sd];
        const float4 wqv = *(const float4*)&wq [(size_t)(e0 + sr) * 256 + dc + sd];
        const float4 wkv = *(const float4*)&wk [(size_t)(e0 + sr) * 256 + dc + sd];
        __syncthreads();
        Hs [sd + 0][sr] = xv.x + pv.x;
        Hs [sd + 1][sr] = xv.y + pv.y;
        Hs [sd + 2][sr] = xv.z + pv.z;
        Hs [sd + 3][sr] = xv.w + pv.w;
        WsQ[sd + 0][sr] = wqv.x;
        WsQ[sd + 1][sr] = wqv.y;
        WsQ[sd + 2][sr] = wqv.z;
        WsQ[sd + 3][sr] = wqv.w;
        WsK[sd + 0][sr] = wkv.x;
        WsK[sd + 1][sr] = wkv.y;
        WsK[sd + 2][sr] = wkv.z;
        WsK[sd + 3][sr] = wkv.w;
        __syncthreads();
        #pragma unroll
        for (int d = 0; d < 16; ++d) {
            const float4 rv = *(const float4*)&Hs [d][ty << 2];
            const float4 eq = *(const float4*)&WsQ[d][tx << 2];
            const float4 ek = *(const float4*)&WsK[d][tx << 2];
            const float a4[4] = {rv.x, rv.y, rv.z, rv.w};
            const float q4[4] = {eq.x, eq.y, eq.z, eq.w};
            const float k4[4] = {ek.x, ek.y, ek.z, ek.w};
            #pragma unroll
            for (int i = 0; i < 4; ++i)
                #pragma unroll
                for (int j = 0; j < 4; ++j) {
                    accQ[i][j] = fmaf(a4[i], q4[j], accQ[i][j]);
                    accK[i][j] = fmaf(a4[i], k4[j], accK[i][j]);
                }
        }
    }

    const float4 bq4 = *(const float4*)&bq[e0 + (tx << 2)];
    const float4 bk4 = *(const float4*)&bk[e0 + (tx << 2)];
    const float bbq[4] = {bq4.x, bq4.y, bq4.z, bq4.w};
    const float bbk[4] = {bk4.x, bk4.y, bk4.z, bk4.w};
    #pragma unroll
    for (int i = 0; i < 4; ++i)
        #pragma unroll
        for (int j = 0; j < 4; ++j) {
            accQ[i][j] += bbq[j];
            accK[i][j] += bbk[j];
        }

    // fragment-tiled plane stores: e = e0+4tx+j -> c,lh,i0 fixed per thread
    const int e_lo = e0 + (tx << 2);
    const int c0   = e_lo >> 5;
    const int lh0  = (e_lo >> 3) & 3;
    const int i0   = e_lo & 7;                 // 0 or 4
    #pragma unroll
    for (int i = 0; i < 4; ++i) {
        const int row = rowBase + (ty << 2) + i;
        const size_t addr = (size_t)(row >> 4) * 4096 + c0 * 512 + lh0 * 128
                          + (size_t)(row & 15) * 8 + i0;
        short4v qh4, ql4, kh4, kl4;
        #pragma unroll
        for (int j = 0; j < 4; ++j) {
            unsigned short h, l;
            bf16_split(accQ[i][j], h, l);
            qh4[j] = (short)h; ql4[j] = (short)l;
            bf16_split(accK[i][j], h, l);
            kh4[j] = (short)h; kl4[j] = (short)l;
        }
        *(short4v*)&Qh[addr] = qh4;
        *(short4v*)&Ql[addr] = ql4;
        *(short4v*)&Kh[addr] = kh4;
        *(short4v*)&Kl[addr] = kl4;
    }
}

// ---------------------------------------------------------------------------
// Kernel B1 v17: batched score GEMM, LDS-free / barrier-free / perm-free.
// Block = (b, tr, tc) 64x64 tile, 4 waves; wave w owns rows 16w..16w+15.
// Fragments load directly from the fragment-tiled planes: per chunk per
// wave = 10 coalesced 1KB loads (L2-resident) + 12 MFMA. Same bf16 values,
// same MFMA order as v13-v16 -> bit-identical scores.
// ---------------------------------------------------------------------------
__global__ __launch_bounds__(256, 4) void score_kernel(
    const unsigned short* __restrict__ Qh, const unsigned short* __restrict__ Ql,
    const unsigned short* __restrict__ Kh, const unsigned short* __restrict__ Kl,
    float* __restrict__ out)
{
    const int tid  = threadIdx.x;
    const int lane = tid & 63;
    const int w    = tid >> 6;        // 0..3
    const int lr   = lane & 15;
    const int lh   = lane >> 4;
    const int bid  = ((blockIdx.x & 7) << 10) + (blockIdx.x >> 3);  // XCD swz
    const int b    = bid >> 8;
    const int tr   = (bid >> 4) & 15;
    const int tc   = bid & 15;

    const int rtA = (b << 6) + (tr << 2) + w;      // A row-tile (global)
    const int rtB0 = (b << 6) + (tc << 2);         // first B row-tile

    const size_t laneOff = (size_t)lh * 128 + (size_t)lr * 8;
    const unsigned short* __restrict__ qhp = Qh + (size_t)rtA * 4096 + laneOff;
    const unsigned short* __restrict__ qlp = Ql + (size_t)rtA * 4096 + laneOff;
    const unsigned short* __restrict__ khp = Kh + (size_t)rtB0 * 4096 + laneOff;
    const unsigned short* __restrict__ klp = Kl + (size_t)rtB0 * 4096 + laneOff;

    f32x4 acc[4];
    #pragma unroll
    for (int ct = 0; ct < 4; ++ct) acc[ct] = (f32x4){0.f, 0.f, 0.f, 0.f};

    #pragma unroll 2
    for (int c = 0; c < 8; ++c) {
        union { bf16x8 v; uint4 u; } qh, ql;
        qh.u = *(const uint4*)(qhp + (size_t)c * 512);
        ql.u = *(const uint4*)(qlp + (size_t)c * 512);
        #pragma unroll
        for (int ct = 0; ct < 4; ++ct) {
            union { bf16x8 v; uint4 u; } kh, kl;
            kh.u = *(const uint4*)(khp + (size_t)ct * 4096 + (size_t)c * 512);
            kl.u = *(const uint4*)(klp + (size_t)ct * 4096 + (size_t)c * 512);
            acc[ct] = __builtin_amdgcn_mfma_f32_16x16x32_bf16(qh.v, kh.v, acc[ct], 0, 0, 0);
            acc[ct] = __builtin_amdgcn_mfma_f32_16x16x32_bf16(qh.v, kl.v, acc[ct], 0, 0, 0);
            acc[ct] = __builtin_amdgcn_mfma_f32_16x16x32_bf16(ql.v, kh.v, acc[ct], 0, 0, 0);
        }
    }

    // D layout (hw-verified): tile row = lh*4 + reg, tile col = lr.
    const int orow = (b << 10) + (tr << 6) + (w << 4) + (lh << 2);
    const int ocol = (tc << 6) + lr;
    #pragma unroll
    for (int ct = 0; ct < 4; ++ct) {
        float* op = out + (size_t)orow * 1024 + ocol + (ct << 4);
        op[0]                 = acc[ct].x;
        op[(size_t)1024]      = acc[ct].y;
        op[(size_t)2048]      = acc[ct].z;
        op[(size_t)3072]      = acc[ct].w;
    }
}

// ---------------------------------------------------------------------------
// Kernel B2 (v13 verbatim): softmax + top-16, in-place on out.
// ---------------------------------------------------------------------------
__global__ __launch_bounds__(256, 4) void topk_kernel(float* __restrict__ out)
{
    const int tid  = threadIdx.x;
    const int lane = tid & 63;
    const int w    = tid >> 6;
    const int rowBase = (int)(blockIdx.x << 3);

    float* __restrict__ r0p = out + (size_t)(rowBase + (w << 1) + 0) * 1024;
    float* __restrict__ r1p = out + (size_t)(rowBase + (w << 1) + 1) * 1024;

    float s0[16], s1[16];
    #pragma unroll
    for (int o = 0; o < 4; ++o) {
        const float4 a = *(const float4*)&r0p[(o << 8) + (lane << 2)];
        const float4 c = *(const float4*)&r1p[(o << 8) + (lane << 2)];
        s0[(o << 2) + 0] = a.x * 0.0625f;
        s0[(o << 2) + 1] = a.y * 0.0625f;
        s0[(o << 2) + 2] = a.z * 0.0625f;
        s0[(o << 2) + 3] = a.w * 0.0625f;
        s1[(o << 2) + 0] = c.x * 0.0625f;
        s1[(o << 2) + 1] = c.y * 0.0625f;
        s1[(o << 2) + 2] = c.z * 0.0625f;
        s1[(o << 2) + 3] = c.w * 0.0625f;
    }

    // row max (wave butterfly), both rows interleaved
    float mx0 = s0[0], mx1 = s1[0];
    #pragma unroll
    for (int i = 1; i < 16; ++i) {
        mx0 = fmaxf(mx0, s0[i]);
        mx1 = fmaxf(mx1, s1[i]);
    }
    #pragma unroll
    for (int off = 32; off > 0; off >>= 1) {
        mx0 = fmaxf(mx0, __shfl_xor(mx0, off));
        mx1 = fmaxf(mx1, __shfl_xor(mx1, off));
    }

    // softmax denominator
    float ls0 = 0.f, ls1 = 0.f;
    #pragma unroll
    for (int i = 0; i < 16; ++i) {
        ls0 += __expf(s0[i] - mx0);
        ls1 += __expf(s1[i] - mx1);
    }
    #pragma unroll
    for (int off = 32; off > 0; off >>= 1) {
        ls0 += __shfl_xor(ls0, off);
        ls1 += __shfl_xor(ls1, off);
    }
    const float rZ0 = 1.0f / ls0;
    const float rZ1 = 1.0f / ls1;

    // top-16 extraction on working copies; winners -> bitmasks
    float wv0[16], wv1[16];
    #pragma unroll
    for (int i = 0; i < 16; ++i) { wv0[i] = s0[i]; wv1[i] = s1[i]; }
    unsigned mask0 = 0u, mask1 = 0u;

    #pragma unroll 1
    for (int j = 0; j < KNNK; ++j) {
        float bv0 = wv0[0], bv1 = wv1[0];
        int   bi0 = 0,      bi1 = 0;
        #pragma unroll
        for (int i = 1; i < 16; ++i) {
            const bool c0 = wv0[i] > bv0;   // strict >, ascending slot scan
            bv0 = c0 ? wv0[i] : bv0;
            bi0 = c0 ? i      : bi0;
            const bool c1 = wv1[i] > bv1;
            bv1 = c1 ? wv1[i] : bv1;
            bi1 = c1 ? i      : bi1;
        }
        const int bm0 = ((bi0 >> 2) << 8) + (lane << 2) + (bi0 & 3);
        const int bm1 = ((bi1 >> 2) << 8) + (lane << 2) + (bi1 & 3);
        const unsigned ub0   = __float_as_uint(bv0);
        const unsigned ub1   = __float_as_uint(bv1);
        const unsigned mono0 = ub0 ^ (unsigned)(((int)ub0 >> 31) | 0x80000000);
        const unsigned mono1 = ub1 ^ (unsigned)(((int)ub1 >> 31) | 0x80000000);
        const unsigned long long key0 =
            ((unsigned long long)mono0 << 32) | (unsigned)(~bm0);
        const unsigned long long key1 =
            ((unsigned long long)mono1 << 32) | (unsigned)(~bm1);
        unsigned long long gk0 = key0, gk1 = key1;
        #pragma unroll
        for (int off = 32; off > 0; off >>= 1) {
            const unsigned long long o0 = __shfl_xor(gk0, off);
            const unsigned long long o1 = __shfl_xor(gk1, off);
            gk0 = (o0 > gk0) ? o0 : gk0;
            gk1 = (o1 > gk1) ? o1 : gk1;
        }
        if (key0 == gk0) {               // unique winner lane, row 0
            mask0 |= (1u << bi0);
            #pragma unroll
            for (int i = 0; i < 16; ++i)
                wv0[i] = (i == bi0) ? -__builtin_inff() : wv0[i];
        }
        if (key1 == gk1) {               // unique winner lane, row 1
            mask1 |= (1u << bi1);
            #pragma unroll
            for (int i = 0; i < 16; ++i)
                wv1[i] = (i == bi1) ? -__builtin_inff() : wv1[i];
        }
    }

    // full-coverage coalesced writes from pristine s0/s1
    #pragma unroll
    for (int o = 0; o < 4; ++o) {
        float4 v;
        v.x = ((mask0 >> ((o << 2) + 0)) & 1u) ? __expf(s0[(o << 2) + 0] - mx0) * rZ0 : 0.f;
        v.y = ((mask0 >> ((o << 2) + 1)) & 1u) ? __expf(s0[(o << 2) + 1] - mx0) * rZ0 : 0.f;
        v.z = ((mask0 >> ((o << 2) + 2)) & 1u) ? __expf(s0[(o << 2) + 2] - mx0) * rZ0 : 0.f;
        v.w = ((mask0 >> ((o << 2) + 3)) & 1u) ? __expf(s0[(o << 2) + 3] - mx0) * rZ0 : 0.f;
        *(float4*)&r0p[(lane << 2) + (o << 8)] = v;
    }
    #pragma unroll
    for (int o = 0; o < 4; ++o) {
        float4 v;
        v.x = ((mask1 >> ((o << 2) + 0)) & 1u) ? __expf(s1[(o << 2) + 0] - mx1) * rZ1 : 0.f;
        v.y = ((mask1 >> ((o << 2) + 1)) & 1u) ? __expf(s1[(o << 2) + 1] - mx1) * rZ1 : 0.f;
        v.z = ((mask1 >> ((o << 2) + 2)) & 1u) ? __expf(s1[(o << 2) + 2] - mx1) * rZ1 : 0.f;
        v.w = ((mask1 >> ((o << 2) + 3)) & 1u) ? __expf(s1[(o << 2) + 3] - mx1) * rZ1 : 0.f;
        *(float4*)&r1p[(lane << 2) + (o << 8)] = v;
    }
}

extern "C" void kernel_launch(void* const* d_in, const int* in_sizes, int n_in,
                              void* d_out, int out_size, void* d_ws, size_t ws_size,
                              hipStream_t stream)
{
    const float* x   = (const float*)d_in[0];
    const float* pos = (const float*)d_in[1];
    const float* wq  = (const float*)d_in[2];
    const float* bq  = (const float*)d_in[3];
    const float* wk  = (const float*)d_in[4];
    const float* bk  = (const float*)d_in[5];
    float* out = (float*)d_out;

    const size_t PLANE = (size_t)NB * NN * ND;       // 8M shorts = 16 MiB
    unsigned short* Qh = (unsigned short*)d_ws;
    unsigned short* Ql = Qh + PLANE;
    unsigned short* Kh = Ql + PLANE;
    unsigned short* Kl = Kh + PLANE;

    proj_kernel<<<dim3(2048), dim3(256), 0, stream>>>(x, pos, wq, bq, wk, bk,
                                                      Qh, Ql, Kh, Kl);
    score_kernel<<<dim3(8192), dim3(256), 0, stream>>>(Qh, Ql, Kh, Kl, out);
    topk_kernel<<<dim3(4096), dim3(256), 0, stream>>>(out);
}

// Round 18
// 294.941 us; speedup vs baseline: 1.0504x; 1.0504x over previous
//
#include <hip/hip_runtime.h>
#include <cstdint>
#include <cstddef>

#define NB 32
#define NN 1024
#define ND 256
#define KNNK 16

typedef __attribute__((ext_vector_type(8))) short bf16x8;
typedef __attribute__((ext_vector_type(4))) float f32x4;
typedef __attribute__((ext_vector_type(4))) short short4v;

// Round-to-nearest-even bf16 split (identical arithmetic to v12-v17).
__device__ __forceinline__ void bf16_split(float v, unsigned short& h,
                                           unsigned short& l) {
    uint32_t u  = __float_as_uint(v);
    uint32_t hi = (u + 0x7fffu + ((u >> 16) & 1u)) >> 16;
    float    hf = __uint_as_float(hi << 16);
    uint32_t g  = __float_as_uint(v - hf);
    uint32_t lo = (g + 0x7fffu + ((g >> 16) & 1u)) >> 16;
    h = (unsigned short)hi;
    l = (unsigned short)lo;
}

// Fragment-tiled plane layout (shorts):
//   plane[rt][c][lh][lr][i] ; rt = flat_row>>4, c = e>>5, lh = (e>>3)&3,
//   lr = flat_row&15, i = e&7 ; linear: rt*4096 + c*512 + lh*128 + lr*8 + i
// A (plane, rt, c) segment is 512 contiguous shorts = 1KB; a wave's 64 lanes
// read/stage it as 64 consecutive 16B chunks.

// ---------------------------------------------------------------------------
// Kernel A (v17 verbatim): fused pos-add + dual projection -> 4 bf16 planes
// in fragment-tiled layout (split done once here).
// ---------------------------------------------------------------------------
__global__ __launch_bounds__(256) void proj_kernel(
    const float* __restrict__ x, const float* __restrict__ pos,
    const float* __restrict__ wq, const float* __restrict__ bq,
    const float* __restrict__ wk, const float* __restrict__ bk,
    unsigned short* __restrict__ Qh, unsigned short* __restrict__ Ql,
    unsigned short* __restrict__ Kh, unsigned short* __restrict__ Kl)
{
    __shared__ __align__(16) float Hs [16][68];
    __shared__ __align__(16) float WsQ[16][68];
    __shared__ __align__(16) float WsK[16][68];

    const int tid = threadIdx.x;
    const int tx = tid & 15;          // e microtile index
    const int ty = tid >> 4;          // row microtile index
    const int bm = blockIdx.x >> 2;   // 0..511 row tiles
    const int be = blockIdx.x & 3;    // 0..3 e tiles (both Q and K)
    const int rowBase = bm << 6;      // flattened b*1024 + n
    const int n0 = rowBase & 1023;
    const int e0 = be << 6;

    const int sr = tid >> 2;          // 0..63
    const int sd = (tid & 3) << 2;    // 0,4,8,12

    float accQ[4][4], accK[4][4];
    #pragma unroll
    for (int i = 0; i < 4; ++i)
        #pragma unroll
        for (int j = 0; j < 4; ++j) { accQ[i][j] = 0.0f; accK[i][j] = 0.0f; }

    #pragma unroll 1
    for (int dc = 0; dc < 256; dc += 16) {
        const float4 xv  = *(const float4*)&x  [(size_t)(rowBase + sr) * 256 + dc + sd];
        const float4 pv  = *(const float4*)&pos[(size_t)(n0 + sr) * 256 + dc + sd];
        const float4 wqv = *(const float4*)&wq [(size_t)(e0 + sr) * 256 + dc + sd];
        const float4 wkv = *(const float4*)&wk [(size_t)(e0 + sr) * 256 + dc + sd];
        __syncthreads();
        Hs [sd + 0][sr] = xv.x + pv.x;
        Hs [sd + 1][sr] = xv.y + pv.y;
        Hs [sd + 2][sr] = xv.z + pv.z;
        Hs [sd + 3][sr] = xv.w + pv.w;
        WsQ[sd + 0][sr] = wqv.x;
        WsQ[sd + 1][sr] = wqv.y;
        WsQ[sd + 2][sr] = wqv.z;
        WsQ[sd + 3][sr] = wqv.w;
        WsK[sd + 0][sr] = wkv.x;
        WsK[sd + 1][sr] = wkv.y;
        WsK[sd + 2][sr] = wkv.z;
        WsK[sd + 3][sr] = wkv.w;
        __syncthreads();
        #pragma unroll
        for (int d = 0; d < 16; ++d) {
            const float4 rv = *(const float4*)&Hs [d][ty << 2];
            const float4 eq = *(const float4*)&WsQ[d][tx << 2];
            const float4 ek = *(const float4*)&WsK[d][tx << 2];
            const float a4[4] = {rv.x, rv.y, rv.z, rv.w};
            const float q4[4] = {eq.x, eq.y, eq.z, eq.w};
            const float k4[4] = {ek.x, ek.y, ek.z, ek.w};
            #pragma unroll
            for (int i = 0; i < 4; ++i)
                #pragma unroll
                for (int j = 0; j < 4; ++j) {
                    accQ[i][j] = fmaf(a4[i], q4[j], accQ[i][j]);
                    accK[i][j] = fmaf(a4[i], k4[j], accK[i][j]);
                }
        }
    }

    const float4 bq4 = *(const float4*)&bq[e0 + (tx << 2)];
    const float4 bk4 = *(const float4*)&bk[e0 + (tx << 2)];
    const float bbq[4] = {bq4.x, bq4.y, bq4.z, bq4.w};
    const float bbk[4] = {bk4.x, bk4.y, bk4.z, bk4.w};
    #pragma unroll
    for (int i = 0; i < 4; ++i)
        #pragma unroll
        for (int j = 0; j < 4; ++j) {
            accQ[i][j] += bbq[j];
            accK[i][j] += bbk[j];
        }

    const int e_lo = e0 + (tx << 2);
    const int c0   = e_lo >> 5;
    const int lh0  = (e_lo >> 3) & 3;
    const int i0   = e_lo & 7;                 // 0 or 4
    #pragma unroll
    for (int i = 0; i < 4; ++i) {
        const int row = rowBase + (ty << 2) + i;
        const size_t addr = (size_t)(row >> 4) * 4096 + c0 * 512 + lh0 * 128
                          + (size_t)(row & 15) * 8 + i0;
        short4v qh4, ql4, kh4, kl4;
        #pragma unroll
        for (int j = 0; j < 4; ++j) {
            unsigned short h, l;
            bf16_split(accQ[i][j], h, l);
            qh4[j] = (short)h; ql4[j] = (short)l;
            bf16_split(accK[i][j], h, l);
            kh4[j] = (short)h; kl4[j] = (short)l;
        }
        *(short4v*)&Qh[addr] = qh4;
        *(short4v*)&Ql[addr] = ql4;
        *(short4v*)&Kh[addr] = kh4;
        *(short4v*)&Kl[addr] = kl4;
    }
}

// ---------------------------------------------------------------------------
// Kernel B1 v18: batched score GEMM = v13's LDS-staged structure (B shared
// by all 4 waves, 4 coalesced uint4 loads/thread/chunk, reg->LDS prefetch)
// + v17's pre-split fragment planes (ZERO v_perm in the loop; fragment
// reads are contiguous ds_read_b128). MFMA values and order bit-identical
// to v13-v17 -> absmax must stay exactly 0.01257324.
// ---------------------------------------------------------------------------
__global__ __launch_bounds__(256, 4) void score_kernel(
    const unsigned short* __restrict__ Qh, const unsigned short* __restrict__ Ql,
    const unsigned short* __restrict__ Kh, const unsigned short* __restrict__ Kl,
    float* __restrict__ out)
{
    __shared__ __align__(16) unsigned short AhL[4][512];   // 4 KB each
    __shared__ __align__(16) unsigned short AlL[4][512];
    __shared__ __align__(16) unsigned short BhL[4][512];
    __shared__ __align__(16) unsigned short BlL[4][512];

    const int tid  = threadIdx.x;
    const int lane = tid & 63;
    const int w    = tid >> 6;        // 0..3 (also staging rt index)
    const int lr   = lane & 15;
    const int lh   = lane >> 4;
    const int bid  = ((blockIdx.x & 7) << 10) + (blockIdx.x >> 3);  // XCD swz
    const int b    = bid >> 8;
    const int tr   = (bid >> 4) & 15;
    const int tc   = bid & 15;

    // staging source pointers: thread stages 16B of (plane, rt=w, chunk c)
    const size_t sOff = (size_t)lane * 8;
    const unsigned short* __restrict__ qhs = Qh + (size_t)((b << 6) + (tr << 2) + w) * 4096 + sOff;
    const unsigned short* __restrict__ qls = Ql + (size_t)((b << 6) + (tr << 2) + w) * 4096 + sOff;
    const unsigned short* __restrict__ khs = Kh + (size_t)((b << 6) + (tc << 2) + w) * 4096 + sOff;
    const unsigned short* __restrict__ kls = Kl + (size_t)((b << 6) + (tc << 2) + w) * 4096 + sOff;

    f32x4 acc[4];
    #pragma unroll
    for (int ct = 0; ct < 4; ++ct) acc[ct] = (f32x4){0.f, 0.f, 0.f, 0.f};

    // prologue: chunk 0 staging regs
    uint4 rAh = *(const uint4*)(qhs);
    uint4 rAl = *(const uint4*)(qls);
    uint4 rBh = *(const uint4*)(khs);
    uint4 rBl = *(const uint4*)(kls);

    #pragma unroll 1
    for (int c = 0; c < 8; ++c) {
        __syncthreads();              // previous chunk's LDS reads complete
        *(uint4*)&AhL[w][lane << 3] = rAh;
        *(uint4*)&AlL[w][lane << 3] = rAl;
        *(uint4*)&BhL[w][lane << 3] = rBh;
        *(uint4*)&BlL[w][lane << 3] = rBl;
        __syncthreads();

        if (c < 7) {                  // prefetch next chunk (overlaps compute)
            const size_t off = (size_t)(c + 1) * 512;
            rAh = *(const uint4*)(qhs + off);
            rAl = *(const uint4*)(qls + off);
            rBh = *(const uint4*)(khs + off);
            rBl = *(const uint4*)(kls + off);
        }

        // ---- A fragment (wave's own rt) ----
        union { bf16x8 v; uint4 u; } qh_, ql_;
        qh_.u = *(const uint4*)&AhL[w][lane << 3];
        ql_.u = *(const uint4*)&AlL[w][lane << 3];

        #pragma unroll
        for (int ct = 0; ct < 4; ++ct) {
            union { bf16x8 v; uint4 u; } kh_, kl_;
            kh_.u = *(const uint4*)&BhL[ct][lane << 3];
            kl_.u = *(const uint4*)&BlL[ct][lane << 3];
            acc[ct] = __builtin_amdgcn_mfma_f32_16x16x32_bf16(qh_.v, kh_.v, acc[ct], 0, 0, 0);
            acc[ct] = __builtin_amdgcn_mfma_f32_16x16x32_bf16(qh_.v, kl_.v, acc[ct], 0, 0, 0);
            acc[ct] = __builtin_amdgcn_mfma_f32_16x16x32_bf16(ql_.v, kh_.v, acc[ct], 0, 0, 0);
        }
    }

    // D layout (hw-verified): tile row = lh*4 + reg, tile col = lr.
    const int orow = (b << 10) + (tr << 6) + (w << 4) + (lh << 2);
    const int ocol = (tc << 6) + lr;
    #pragma unroll
    for (int ct = 0; ct < 4; ++ct) {
        float* op = out + (size_t)orow * 1024 + ocol + (ct << 4);
        op[0]                 = acc[ct].x;
        op[(size_t)1024]      = acc[ct].y;
        op[(size_t)2048]      = acc[ct].z;
        op[(size_t)3072]      = acc[ct].w;
    }
}

// ---------------------------------------------------------------------------
// Kernel B2 (v13 verbatim): softmax + top-16, in-place on out.
// ---------------------------------------------------------------------------
__global__ __launch_bounds__(256, 4) void topk_kernel(float* __restrict__ out)
{
    const int tid  = threadIdx.x;
    const int lane = tid & 63;
    const int w    = tid >> 6;
    const int rowBase = (int)(blockIdx.x << 3);

    float* __restrict__ r0p = out + (size_t)(rowBase + (w << 1) + 0) * 1024;
    float* __restrict__ r1p = out + (size_t)(rowBase + (w << 1) + 1) * 1024;

    float s0[16], s1[16];
    #pragma unroll
    for (int o = 0; o < 4; ++o) {
        const float4 a = *(const float4*)&r0p[(o << 8) + (lane << 2)];
        const float4 c = *(const float4*)&r1p[(o << 8) + (lane << 2)];
        s0[(o << 2) + 0] = a.x * 0.0625f;
        s0[(o << 2) + 1] = a.y * 0.0625f;
        s0[(o << 2) + 2] = a.z * 0.0625f;
        s0[(o << 2) + 3] = a.w * 0.0625f;
        s1[(o << 2) + 0] = c.x * 0.0625f;
        s1[(o << 2) + 1] = c.y * 0.0625f;
        s1[(o << 2) + 2] = c.z * 0.0625f;
        s1[(o << 2) + 3] = c.w * 0.0625f;
    }

    // row max (wave butterfly), both rows interleaved
    float mx0 = s0[0], mx1 = s1[0];
    #pragma unroll
    for (int i = 1; i < 16; ++i) {
        mx0 = fmaxf(mx0, s0[i]);
        mx1 = fmaxf(mx1, s1[i]);
    }
    #pragma unroll
    for (int off = 32; off > 0; off >>= 1) {
        mx0 = fmaxf(mx0, __shfl_xor(mx0, off));
        mx1 = fmaxf(mx1, __shfl_xor(mx1, off));
    }

    // softmax denominator
    float ls0 = 0.f, ls1 = 0.f;
    #pragma unroll
    for (int i = 0; i < 16; ++i) {
        ls0 += __expf(s0[i] - mx0);
        ls1 += __expf(s1[i] - mx1);
    }
    #pragma unroll
    for (int off = 32; off > 0; off >>= 1) {
        ls0 += __shfl_xor(ls0, off);
        ls1 += __shfl_xor(ls1, off);
    }
    const float rZ0 = 1.0f / ls0;
    const float rZ1 = 1.0f / ls1;

    // top-16 extraction on working copies; winners -> bitmasks
    float wv0[16], wv1[16];
    #pragma unroll
    for (int i = 0; i < 16; ++i) { wv0[i] = s0[i]; wv1[i] = s1[i]; }
    unsigned mask0 = 0u, mask1 = 0u;

    #pragma unroll 1
    for (int j = 0; j < KNNK; ++j) {
        float bv0 = wv0[0], bv1 = wv1[0];
        int   bi0 = 0,      bi1 = 0;
        #pragma unroll
        for (int i = 1; i < 16; ++i) {
            const bool c0 = wv0[i] > bv0;   // strict >, ascending slot scan
            bv0 = c0 ? wv0[i] : bv0;
            bi0 = c0 ? i      : bi0;
            const bool c1 = wv1[i] > bv1;
            bv1 = c1 ? wv1[i] : bv1;
            bi1 = c1 ? i      : bi1;
        }
        const int bm0 = ((bi0 >> 2) << 8) + (lane << 2) + (bi0 & 3);
        const int bm1 = ((bi1 >> 2) << 8) + (lane << 2) + (bi1 & 3);
        const unsigned ub0   = __float_as_uint(bv0);
        const unsigned ub1   = __float_as_uint(bv1);
        const unsigned mono0 = ub0 ^ (unsigned)(((int)ub0 >> 31) | 0x80000000);
        const unsigned mono1 = ub1 ^ (unsigned)(((int)ub1 >> 31) | 0x80000000);
        const unsigned long long key0 =
            ((unsigned long long)mono0 << 32) | (unsigned)(~bm0);
        const unsigned long long key1 =
            ((unsigned long long)mono1 << 32) | (unsigned)(~bm1);
        unsigned long long gk0 = key0, gk1 = key1;
        #pragma unroll
        for (int off = 32; off > 0; off >>= 1) {
            const unsigned long long o0 = __shfl_xor(gk0, off);
            const unsigned long long o1 = __shfl_xor(gk1, off);
            gk0 = (o0 > gk0) ? o0 : gk0;
            gk1 = (o1 > gk1) ? o1 : gk1;
        }
        if (key0 == gk0) {               // unique winner lane, row 0
            mask0 |= (1u << bi0);
            #pragma unroll
            for (int i = 0; i < 16; ++i)
                wv0[i] = (i == bi0) ? -__builtin_inff() : wv0[i];
        }
        if (key1 == gk1) {               // unique winner lane, row 1
            mask1 |= (1u << bi1);
            #pragma unroll
            for (int i = 0; i < 16; ++i)
                wv1[i] = (i == bi1) ? -__builtin_inff() : wv1[i];
        }
    }

    // full-coverage coalesced writes from pristine s0/s1
    #pragma unroll
    for (int o = 0; o < 4; ++o) {
        float4 v;
        v.x = ((mask0 >> ((o << 2) + 0)) & 1u) ? __expf(s0[(o << 2) + 0] - mx0) * rZ0 : 0.f;
        v.y = ((mask0 >> ((o << 2) + 1)) & 1u) ? __expf(s0[(o << 2) + 1] - mx0) * rZ0 : 0.f;
        v.z = ((mask0 >> ((o << 2) + 2)) & 1u) ? __expf(s0[(o << 2) + 2] - mx0) * rZ0 : 0.f;
        v.w = ((mask0 >> ((o << 2) + 3)) & 1u) ? __expf(s0[(o << 2) + 3] - mx0) * rZ0 : 0.f;
        *(float4*)&r0p[(lane << 2) + (o << 8)] = v;
    }
    #pragma unroll
    for (int o = 0; o < 4; ++o) {
        float4 v;
        v.x = ((mask1 >> ((o << 2) + 0)) & 1u) ? __expf(s1[(o << 2) + 0] - mx1) * rZ1 : 0.f;
        v.y = ((mask1 >> ((o << 2) + 1)) & 1u) ? __expf(s1[(o << 2) + 1] - mx1) * rZ1 : 0.f;
        v.z = ((mask1 >> ((o << 2) + 2)) & 1u) ? __expf(s1[(o << 2) + 2] - mx1) * rZ1 : 0.f;
        v.w = ((mask1 >> ((o << 2) + 3)) & 1u) ? __expf(s1[(o << 2) + 3] - mx1) * rZ1 : 0.f;
        *(float4*)&r1p[(lane << 2) + (o << 8)] = v;
    }
}

extern "C" void kernel_launch(void* const* d_in, const int* in_sizes, int n_in,
                              void* d_out, int out_size, void* d_ws, size_t ws_size,
                              hipStream_t stream)
{
    const float* x   = (const float*)d_in[0];
    const float* pos = (const float*)d_in[1];
    const float* wq  = (const float*)d_in[2];
    const float* bq  = (const float*)d_in[3];
    const float* wk  = (const float*)d_in[4];
    const float* bk  = (const float*)d_in[5];
    float* out = (float*)d_out;

    const size_t PLANE = (size_t)NB * NN * ND;       // 8M shorts = 16 MiB
    unsigned short* Qh = (unsigned short*)d_ws;
    unsigned short* Ql = Qh + PLANE;
    unsigned short* Kh = Ql + PLANE;
    unsigned short* Kl = Kh + PLANE;

    proj_kernel<<<dim3(2048), dim3(256), 0, stream>>>(x, pos, wq, bq, wk, bk,
                                                      Qh, Ql, Kh, Kl);
    score_kernel<<<dim3(8192), dim3(256), 0, stream>>>(Qh, Ql, Kh, Kl, out);
    topk_kernel<<<dim3(4096), dim3(256), 0, stream>>>(out);
}